// Round 2
// baseline (130.753 us; speedup 1.0000x reference)
//
#include <hip/hip_runtime.h>

#define CC 64
#define HWSZ 4096
#define CHWSZ 262144
#define NE 512
#define NPIX 131072
#define PIXB 128

#define E2_OFF 0
#define HIST_OFF 2048
#define BATCH_OFF 4096

// ---- init: e2[512] (numpy axis-0 sequential reduce of rounded squares), zero hist/batch ----
__global__ __launch_bounds__(512) void vq_init(const float* __restrict__ eg, char* __restrict__ ws) {
    const int n = threadIdx.x;
    float s = 0.f;
    #pragma unroll 8
    for (int k = 0; k < CC; ++k) {
        float v = eg[k * NE + n];
        s = __fadd_rn(s, __fmul_rn(v, v));
    }
    ((float*)(ws + E2_OFF))[n] = s;
    ((unsigned int*)(ws + HIST_OFF))[n] = 0u;
    if (n < 32) ((float*)(ws + BATCH_OFF))[n] = 0.f;
}

// ---- main: fp32 VALU GEMM-argmin, 128 pixels/block, 8x8 register tile ----
__global__ __launch_bounds__(256) void vq_main(const float* __restrict__ xg,
                                               const float* __restrict__ eg,
                                               float* __restrict__ outg,
                                               char* __restrict__ ws) {
    __shared__ float xa[CC][PIXB];     // [k][pixel]
    __shared__ float eb[CC][128];      // [k][code_local]
    __shared__ float f2s[PIXB];
    __shared__ float e2s[128];
    __shared__ int idxs[PIXB];
    __shared__ unsigned int hist[NE];
    __shared__ float wsum[4];

    const int tid  = threadIdx.x;
    const int lane = tid & 63;
    const int wv   = tid >> 6;
    const int i    = tid >> 4;      // pixel group 0..15
    const int j    = tid & 15;      // code group 0..15
    const int pix0 = blockIdx.x * PIXB;
    const int bb   = pix0 >> 12;
    const int hw0  = pix0 & 4095;
    const size_t xbase = (size_t)bb * CHWSZ + hw0;

    // stage x tile (coalesced float4; global layout is already [k][pixel])
    for (int t = tid; t < 2048; t += 256) {
        int k = t >> 5, p4 = (t & 31) << 2;
        *(float4*)&xa[k][p4] = *(const float4*)(xg + xbase + (size_t)k * HWSZ + p4);
    }
    for (int t = tid; t < NE; t += 256) hist[t] = 0u;
    __syncthreads();

    // f2 per pixel — numpy pairwise 8-accumulator pattern over 64 rounded squares
    if (tid < PIXB) {
        float r[8];
        #pragma unroll
        for (int u = 0; u < 8; ++u) { float v = xa[u][tid]; r[u] = __fmul_rn(v, v); }
        #pragma unroll
        for (int t = 1; t < 8; ++t)
            #pragma unroll
            for (int u = 0; u < 8; ++u) { float v = xa[t * 8 + u][tid]; r[u] = __fadd_rn(r[u], __fmul_rn(v, v)); }
        float c0 = __fadd_rn(__fadd_rn(r[0], r[1]), __fadd_rn(r[2], r[3]));
        float c1 = __fadd_rn(__fadd_rn(r[4], r[5]), __fadd_rn(r[6], r[7]));
        f2s[tid] = __fadd_rn(c0, c1);
    }

    float minv[8];
    int   mini[8];
    #pragma unroll
    for (int a = 0; a < 8; ++a) { minv[a] = 3.4e38f; mini[a] = 0; }

    const float* e2g = (const float*)(ws + E2_OFF);

    for (int ct = 0; ct < 4; ++ct) {
        for (int t = tid; t < 2048; t += 256) {
            int k = t >> 5, n4 = (t & 31) << 2;
            *(float4*)&eb[k][n4] = *(const float4*)(eg + k * NE + ct * 128 + n4);
        }
        if (tid < 128) e2s[tid] = e2g[ct * 128 + tid];
        __syncthreads();

        float acc[8][8];
        #pragma unroll
        for (int a = 0; a < 8; ++a)
            #pragma unroll
            for (int b = 0; b < 8; ++b) acc[a][b] = 0.f;

        // sequential-k FMA chain (matches BLAS microkernel accumulation order)
        #pragma unroll 4
        for (int k = 0; k < CC; ++k) {
            float xr[8], er[8];
            *(float4*)&xr[0] = *(const float4*)&xa[k][4 * i];
            *(float4*)&xr[4] = *(const float4*)&xa[k][64 + 4 * i];
            *(float4*)&er[0] = *(const float4*)&eb[k][4 * j];
            *(float4*)&er[4] = *(const float4*)&eb[k][64 + 4 * j];
            #pragma unroll
            for (int a = 0; a < 8; ++a)
                #pragma unroll
                for (int b = 0; b < 8; ++b)
                    acc[a][b] = __fmaf_rn(xr[a], er[b], acc[a][b]);
        }

        // dist = (f2 - 2*dot) + e2, numpy's exact op order; first-min tie-break
        #pragma unroll
        for (int a = 0; a < 8; ++a) {
            int p = (a < 4) ? (4 * i + a) : (60 + 4 * i + a);
            float f2 = f2s[p];
            #pragma unroll
            for (int b = 0; b < 8; ++b) {
                int nl = (b < 4) ? (4 * j + b) : (60 + 4 * j + b);
                float d = __fadd_rn(__fmaf_rn(-2.f, acc[a][b], f2), e2s[nl]);
                int code = ct * 128 + nl;
                if (d < minv[a]) { minv[a] = d; mini[a] = code; }
            }
        }
        __syncthreads();
    }

    // cross-thread reduce over the 16 code-groups (lanes (i&3)*16 + j), index tie-break
    #pragma unroll
    for (int m = 1; m < 16; m <<= 1) {
        #pragma unroll
        for (int a = 0; a < 8; ++a) {
            float ov = __shfl_xor(minv[a], m, 64);
            int   oi = __shfl_xor(mini[a], m, 64);
            if (ov < minv[a] || (ov == minv[a] && oi < mini[a])) { minv[a] = ov; mini[a] = oi; }
        }
    }
    if (j == 0) {
        #pragma unroll
        for (int a = 0; a < 8; ++a) {
            int p = (a < 4) ? (4 * i + a) : (60 + 4 * i + a);
            idxs[p] = mini[a];
            atomicAdd(&hist[mini[a]], 1u);
        }
    }
    __syncthreads();

    unsigned int* ghist = (unsigned int*)(ws + HIST_OFF);
    for (int t = tid; t < NE; t += 256) { unsigned int c = hist[t]; if (c) atomicAdd(&ghist[t], c); }

    // epilogue: out = x + (q - x) (ref op order), per-batch sq accumulation
    float sq = 0.f;
    for (int t = tid; t < 8192; t += 256) {
        int c = t >> 7, p = t & 127;
        int code = idxs[p];
        float q = eg[c * NE + code];
        float xv = xa[c][p];
        float d = __fsub_rn(q, xv);
        outg[xbase + (size_t)c * HWSZ + p] = __fadd_rn(xv, d);
        sq = __fmaf_rn(d, d, sq);
    }
    #pragma unroll
    for (int m = 32; m >= 1; m >>= 1) sq += __shfl_down(sq, m, 64);
    if (lane == 0) wsum[wv] = sq;
    __syncthreads();
    if (tid == 0) atomicAdd((float*)(ws + BATCH_OFF) + bb, wsum[0] + wsum[1] + wsum[2] + wsum[3]);
}

// ---- finalize: diff[32] and perplexity ----
__global__ __launch_bounds__(512) void vq_fin(const char* __restrict__ ws, float* __restrict__ outg) {
    __shared__ float acc8[8];
    const int tid = threadIdx.x, lane = tid & 63, wv = tid >> 6;
    const unsigned int* ghist = (const unsigned int*)(ws + HIST_OFF);
    float p = (float)ghist[tid] * (1.f / (float)NPIX);
    float t = p * logf(p + 1e-10f);
    #pragma unroll
    for (int m = 32; m >= 1; m >>= 1) t += __shfl_down(t, m, 64);
    if (lane == 0) acc8[wv] = t;
    __syncthreads();
    if (tid < 32) outg[8388608 + tid] = ((const float*)(ws + BATCH_OFF))[tid] * (1.f / 262144.f);
    if (tid == 0) {
        float s = 0.f;
        #pragma unroll
        for (int u = 0; u < 8; ++u) s += acc8[u];
        outg[8388640] = expf(-s);
    }
}

extern "C" void kernel_launch(void* const* d_in, const int* in_sizes, int n_in,
                              void* d_out, int out_size, void* d_ws, size_t ws_size,
                              hipStream_t stream) {
    const float* xg = (const float*)d_in[0];
    const float* eg = (const float*)d_in[1];
    float* outg = (float*)d_out;
    char* ws = (char*)d_ws;
    vq_init<<<1, 512, 0, stream>>>(eg, ws);
    vq_main<<<NPIX / PIXB, 256, 0, stream>>>(xg, eg, outg, ws);
    vq_fin<<<1, 512, 0, stream>>>(ws, outg);
}

// Round 3
// 114.043 us; speedup vs baseline: 1.1465x; 1.1465x over previous
//
#include <hip/hip_runtime.h>

typedef __bf16 bf16x8 __attribute__((ext_vector_type(8)));
typedef float  f32x4  __attribute__((ext_vector_type(4)));

#define CC 64
#define HWSZ 4096
#define CHWSZ 262144
#define NE 512
#define NPIX 131072
#define PIXB 128
#define EPS_MARGIN 0.01f

#define ET_OFF 0            // 512 codes * 256 B (hi[64]|lo[64] bf16)  = 131072
#define E2_OFF 131072       // 512 * 4
#define HIST_OFF 133120     // 512 * 4
#define BATCH_OFF 135168    // 32 * 4

__device__ __forceinline__ float bf2f(unsigned short u) {
    unsigned int x = ((unsigned int)u) << 16;
    return __builtin_bit_cast(float, x);
}
__device__ __forceinline__ unsigned short f2bf(float f) {
    unsigned int x = __builtin_bit_cast(unsigned int, f);
    unsigned int r = x + 0x7fffu + ((x >> 16) & 1u);
    return (unsigned short)(r >> 16);
}

// ---- init: exact e2[512]; embed^T hi/lo planes [code][128] bf16; zero hist/batch ----
__global__ __launch_bounds__(512) void vq_init(const float* __restrict__ eg, char* __restrict__ ws) {
    __shared__ float se[CC * NE];           // 128 KB
    const int tid = threadIdx.x;
    for (int i = tid; i < CC * NE; i += 512) se[i] = eg[i];
    __syncthreads();
    // exact e2 (numpy axis-0 sequential reduce) — must match round-2 arithmetic
    float s = 0.f;
    #pragma unroll 8
    for (int k = 0; k < CC; ++k) { float v = se[k * NE + tid]; s = __fadd_rn(s, __fmul_rn(v, v)); }
    ((float*)(ws + E2_OFF))[tid] = s;
    // et: row n = [hi(k=0..63) | lo(k=0..63)] bf16, row stride 256 B; coalesced u32 writes
    unsigned int* et32 = (unsigned int*)(ws + ET_OFF);
    #pragma unroll 4
    for (int it = 0; it < 64; ++it) {
        int idx = tid + it * 512;
        int n = idx >> 6;
        int kk2 = (idx & 63) << 1;          // element column pair (even, 0..126)
        int k = kk2 & 63;
        float v0 = se[k * NE + n], v1 = se[(k + 1) * NE + n];
        unsigned short c0, c1;
        if (kk2 < 64) { c0 = f2bf(v0); c1 = f2bf(v1); }
        else {
            unsigned short h0 = f2bf(v0), h1 = f2bf(v1);
            c0 = f2bf(__fsub_rn(v0, bf2f(h0)));
            c1 = f2bf(__fsub_rn(v1, bf2f(h1)));
        }
        et32[idx] = (unsigned int)c0 | ((unsigned int)c1 << 16);
    }
    ((unsigned int*)(ws + HIST_OFF))[tid] = 0u;
    if (tid < 32) ((float*)(ws + BATCH_OFF))[tid] = 0.f;
}

// ---- main: split-bf16 MFMA argmin + margin recheck + quantize + loss partials ----
__global__ __launch_bounds__(256) void vq_main(const float* __restrict__ xg,
                                               const float* __restrict__ eg,
                                               float* __restrict__ outg,
                                               char* __restrict__ ws) {
    __shared__ __align__(16) char xtb[PIXB * 256];   // [pixel][hi64|lo64] bf16, XOR-swizzled
    __shared__ __align__(16) char etb[128 * 256];    // [code_local][hi64|lo64], XOR-swizzled
    __shared__ float e2s[128];
    __shared__ int idxs[PIXB];
    __shared__ unsigned int hist[NE];
    __shared__ float wsum[4];
    __shared__ int nflag;
    __shared__ int flist[PIXB];
    __shared__ float xp[CC];
    __shared__ float redv[4];
    __shared__ int redi[4];

    const int tid  = threadIdx.x;
    const int lane = tid & 63;
    const int wv   = tid >> 6;
    const int l15  = lane & 15;
    const int l4   = lane >> 4;
    const int pix0 = blockIdx.x * PIXB;
    const int bb   = pix0 >> 12;
    const int hw0  = pix0 & 4095;
    const size_t xbase = (size_t)bb * CHWSZ + hw0;

    if (tid == 0) nflag = 0;
    for (int t = tid; t < NE; t += 256) hist[t] = 0u;

    // stage x: thread owns pixel p, k-half h; loads wave-coalesced over p
    {
        const int p = tid & 127, h = tid >> 7;
        const int sw = (p & 7) << 4;
        #pragma unroll
        for (int q = 0; q < 8; ++q) {
            int k0 = h * 32 + q * 4;
            float v0 = xg[xbase + (size_t)(k0 + 0) * HWSZ + p];
            float v1 = xg[xbase + (size_t)(k0 + 1) * HWSZ + p];
            float v2 = xg[xbase + (size_t)(k0 + 2) * HWSZ + p];
            float v3 = xg[xbase + (size_t)(k0 + 3) * HWSZ + p];
            unsigned short h0 = f2bf(v0), h1 = f2bf(v1), h2 = f2bf(v2), h3 = f2bf(v3);
            unsigned short o0 = f2bf(__fsub_rn(v0, bf2f(h0)));
            unsigned short o1 = f2bf(__fsub_rn(v1, bf2f(h1)));
            unsigned short o2 = f2bf(__fsub_rn(v2, bf2f(h2)));
            unsigned short o3 = f2bf(__fsub_rn(v3, bf2f(h3)));
            uint2 hw, lw;
            hw.x = (unsigned int)h0 | ((unsigned int)h1 << 16);
            hw.y = (unsigned int)h2 | ((unsigned int)h3 << 16);
            lw.x = (unsigned int)o0 | ((unsigned int)o1 << 16);
            lw.y = (unsigned int)o2 | ((unsigned int)o3 << 16);
            *(uint2*)(xtb + ((p * 256 + 2 * k0) ^ sw)) = hw;
            *(uint2*)(xtb + ((p * 256 + 128 + 2 * k0) ^ sw)) = lw;
        }
    }
    __syncthreads();

    // A fragments (hi and lo), 2 m-tiles per wave
    bf16x8 ah[2][2], al[2][2];
    #pragma unroll
    for (int mt = 0; mt < 2; ++mt) {
        int prow = (2 * wv + mt) * 16 + l15;
        int sw = (prow & 7) << 4;
        #pragma unroll
        for (int kh = 0; kh < 2; ++kh) {
            ah[mt][kh] = *(const bf16x8*)(xtb + ((prow * 256 + kh * 64 + l4 * 16) ^ sw));
            al[mt][kh] = *(const bf16x8*)(xtb + ((prow * 256 + 128 + kh * 64 + l4 * 16) ^ sw));
        }
    }

    float minv[2][4], min2v[2][4];
    int   mini[2][4];
    #pragma unroll
    for (int mt = 0; mt < 2; ++mt)
        #pragma unroll
        for (int r = 0; r < 4; ++r) { minv[mt][r] = 3.4e38f; min2v[mt][r] = 3.4e38f; mini[mt][r] = 0; }

    const char*  etw = ws + ET_OFF;
    const float* e2g = (const float*)(ws + E2_OFF);

    for (int ct = 0; ct < 4; ++ct) {
        __syncthreads();
        for (int u = tid; u < 2048; u += 256) {
            int row = u >> 4, seg = u & 15;
            uint4 v = *(const uint4*)(etw + (size_t)(ct * 128 + row) * 256 + seg * 16);
            *(uint4*)(etb + ((row * 256 + seg * 16) ^ ((row & 7) << 4))) = v;
        }
        if (tid < 128) e2s[tid] = e2g[ct * 128 + tid];
        __syncthreads();

        float e2r[8];
        #pragma unroll
        for (int nt = 0; nt < 8; ++nt) e2r[nt] = e2s[nt * 16 + l15];

        #pragma unroll
        for (int nt = 0; nt < 8; ++nt) {
            int crow = nt * 16 + l15;
            int sw = (crow & 7) << 4;
            bf16x8 bh0 = *(const bf16x8*)(etb + ((crow * 256 +   0 + l4 * 16) ^ sw));
            bf16x8 bh1 = *(const bf16x8*)(etb + ((crow * 256 +  64 + l4 * 16) ^ sw));
            bf16x8 bl0 = *(const bf16x8*)(etb + ((crow * 256 + 128 + l4 * 16) ^ sw));
            bf16x8 bl1 = *(const bf16x8*)(etb + ((crow * 256 + 192 + l4 * 16) ^ sw));
            int code = ct * 128 + nt * 16 + l15;
            #pragma unroll
            for (int mt = 0; mt < 2; ++mt) {
                f32x4 acc = (f32x4){0.f, 0.f, 0.f, 0.f};
                acc = __builtin_amdgcn_mfma_f32_16x16x32_bf16(ah[mt][0], bh0, acc, 0, 0, 0);
                acc = __builtin_amdgcn_mfma_f32_16x16x32_bf16(ah[mt][1], bh1, acc, 0, 0, 0);
                acc = __builtin_amdgcn_mfma_f32_16x16x32_bf16(ah[mt][0], bl0, acc, 0, 0, 0);
                acc = __builtin_amdgcn_mfma_f32_16x16x32_bf16(ah[mt][1], bl1, acc, 0, 0, 0);
                acc = __builtin_amdgcn_mfma_f32_16x16x32_bf16(al[mt][0], bh0, acc, 0, 0, 0);
                acc = __builtin_amdgcn_mfma_f32_16x16x32_bf16(al[mt][1], bh1, acc, 0, 0, 0);
                #pragma unroll
                for (int r = 0; r < 4; ++r) {
                    float d = __fmaf_rn(-2.f, acc[r], e2r[nt]);
                    bool lt = d < minv[mt][r];
                    min2v[mt][r] = fminf(min2v[mt][r], fmaxf(d, minv[mt][r]));
                    minv[mt][r] = lt ? d : minv[mt][r];
                    mini[mt][r] = lt ? code : mini[mt][r];
                }
            }
        }
    }

    // 16-lane argmin reduce with second-min tracking and first-index tie-break
    #pragma unroll
    for (int m = 1; m < 16; m <<= 1) {
        #pragma unroll
        for (int mt = 0; mt < 2; ++mt)
            #pragma unroll
            for (int r = 0; r < 4; ++r) {
                float ov  = __shfl_xor(minv[mt][r], m, 64);
                int   oi  = __shfl_xor(mini[mt][r], m, 64);
                float ov2 = __shfl_xor(min2v[mt][r], m, 64);
                bool sel = (ov < minv[mt][r]) || (ov == minv[mt][r] && oi < mini[mt][r]);
                float big = sel ? minv[mt][r] : ov;
                min2v[mt][r] = fminf(fminf(min2v[mt][r], ov2), big);
                minv[mt][r] = sel ? ov : minv[mt][r];
                mini[mt][r] = sel ? oi : mini[mt][r];
            }
    }
    if (l15 == 0) {
        #pragma unroll
        for (int mt = 0; mt < 2; ++mt)
            #pragma unroll
            for (int r = 0; r < 4; ++r) {
                int p = (2 * wv + mt) * 16 + l4 * 4 + r;
                idxs[p] = mini[mt][r];
                if (min2v[mt][r] - minv[mt][r] < EPS_MARGIN) {
                    int pos = atomicAdd(&nflag, 1);
                    flist[pos] = p;
                }
            }
    }
    __syncthreads();

    // exact recheck for near-tie pixels — bit-identical to round-2 arithmetic
    const int nf = nflag;
    for (int f = 0; f < nf; ++f) {
        int p = flist[f];
        if (tid < CC) xp[tid] = xg[xbase + (size_t)tid * HWSZ + p];
        __syncthreads();
        float rr[8];
        #pragma unroll
        for (int u = 0; u < 8; ++u) { float v = xp[u]; rr[u] = __fmul_rn(v, v); }
        #pragma unroll
        for (int t2 = 1; t2 < 8; ++t2)
            #pragma unroll
            for (int u = 0; u < 8; ++u) { float v = xp[t2 * 8 + u]; rr[u] = __fadd_rn(rr[u], __fmul_rn(v, v)); }
        float f2 = __fadd_rn(__fadd_rn(__fadd_rn(rr[0], rr[1]), __fadd_rn(rr[2], rr[3])),
                             __fadd_rn(__fadd_rn(rr[4], rr[5]), __fadd_rn(rr[6], rr[7])));
        float best = 3.4e38f; int bidx = 0;
        #pragma unroll
        for (int h = 0; h < 2; ++h) {
            int c = h * 256 + tid;
            float dot = 0.f;
            #pragma unroll 8
            for (int k = 0; k < CC; ++k) dot = __fmaf_rn(xp[k], eg[k * NE + c], dot);
            float d = __fadd_rn(__fmaf_rn(-2.f, dot, f2), e2g[c]);
            if (d < best) { best = d; bidx = c; }
        }
        #pragma unroll
        for (int m = 1; m < 64; m <<= 1) {
            float ov = __shfl_xor(best, m, 64);
            int   oi = __shfl_xor(bidx, m, 64);
            if (ov < best || (ov == best && oi < bidx)) { best = ov; bidx = oi; }
        }
        if (lane == 0) { redv[wv] = best; redi[wv] = bidx; }
        __syncthreads();
        if (tid == 0) {
            float bv = redv[0]; int bi = redi[0];
            #pragma unroll
            for (int w = 1; w < 4; ++w)
                if (redv[w] < bv || (redv[w] == bv && redi[w] < bi)) { bv = redv[w]; bi = redi[w]; }
            idxs[p] = bi;
        }
        __syncthreads();
    }

    // histogram from final indices
    if (tid < PIXB) atomicAdd(&hist[idxs[tid]], 1u);
    __syncthreads();
    unsigned int* ghist = (unsigned int*)(ws + HIST_OFF);
    for (int t = tid; t < NE; t += 256) { unsigned int c = hist[t]; if (c) atomicAdd(&ghist[t], c); }

    // epilogue: out = x~ + (q - x~), per-batch sq accumulation (x~ = hi+lo, err ~2^-18)
    float sq = 0.f;
    for (int t = tid; t < 8192; t += 256) {
        int c = t >> 7, p = t & 127;
        int sw = (p & 7) << 4;
        int code = idxs[p];
        float q = eg[c * NE + code];
        float xh = bf2f(*(const unsigned short*)(xtb + ((p * 256 + 2 * c) ^ sw)));
        float xl = bf2f(*(const unsigned short*)(xtb + ((p * 256 + 128 + 2 * c) ^ sw)));
        float xv = __fadd_rn(xh, xl);
        float d = __fsub_rn(q, xv);
        outg[xbase + (size_t)c * HWSZ + p] = __fadd_rn(xv, d);
        sq = __fmaf_rn(d, d, sq);
    }
    #pragma unroll
    for (int m = 32; m >= 1; m >>= 1) sq += __shfl_down(sq, m, 64);
    if (lane == 0) wsum[wv] = sq;
    __syncthreads();
    if (tid == 0) atomicAdd((float*)(ws + BATCH_OFF) + bb, wsum[0] + wsum[1] + wsum[2] + wsum[3]);
}

// ---- finalize: diff[32] and perplexity ----
__global__ __launch_bounds__(512) void vq_fin(const char* __restrict__ ws, float* __restrict__ outg) {
    __shared__ float acc8[8];
    const int tid = threadIdx.x, lane = tid & 63, wv = tid >> 6;
    const unsigned int* ghist = (const unsigned int*)(ws + HIST_OFF);
    float p = (float)ghist[tid] * (1.f / (float)NPIX);
    float t = p * logf(p + 1e-10f);
    #pragma unroll
    for (int m = 32; m >= 1; m >>= 1) t += __shfl_down(t, m, 64);
    if (lane == 0) acc8[wv] = t;
    __syncthreads();
    if (tid < 32) outg[8388608 + tid] = ((const float*)(ws + BATCH_OFF))[tid] * (1.f / 262144.f);
    if (tid == 0) {
        float s = 0.f;
        #pragma unroll
        for (int u = 0; u < 8; ++u) s += acc8[u];
        outg[8388640] = expf(-s);
    }
}

extern "C" void kernel_launch(void* const* d_in, const int* in_sizes, int n_in,
                              void* d_out, int out_size, void* d_ws, size_t ws_size,
                              hipStream_t stream) {
    const float* xg = (const float*)d_in[0];
    const float* eg = (const float*)d_in[1];
    float* outg = (float*)d_out;
    char* ws = (char*)d_ws;
    vq_init<<<1, 512, 0, stream>>>(eg, ws);
    vq_main<<<NPIX / PIXB, 256, 0, stream>>>(xg, eg, outg, ws);
    vq_fin<<<1, 512, 0, stream>>>(ws, outg);
}